// Round 3
// baseline (2364.677 us; speedup 1.0000x reference)
//
#include <hip/hip_runtime.h>
#include <stdint.h>
#include <math.h>

// Problem sizes (fixed by setup_inputs)
#define B_ROWS 4096
#define C_DIM  2048
#define F_DIM  8192
#define HD     512
static const size_t BC = (size_t)B_ROWS * C_DIM;   // 8,388,608

typedef __attribute__((ext_vector_type(8))) short  short8;
typedef __attribute__((ext_vector_type(8))) __bf16 bf16x8;
typedef __attribute__((ext_vector_type(4))) float  f32x4;
typedef __attribute__((ext_vector_type(4))) unsigned short us4;
typedef unsigned short u16;

union F4 { float4 v; float f[4]; };

// ---- bf16 split helpers -----------------------------------------------------
__device__ __forceinline__ u16 bf16_rn(float x) {
  uint32_t u = __builtin_bit_cast(uint32_t, x);
  return (u16)((u + 0x7FFFu + ((u >> 16) & 1u)) >> 16);
}
__device__ __forceinline__ float bf16f(u16 h) {
  uint32_t u = (uint32_t)h << 16;
  return __builtin_bit_cast(float, u);
}
__device__ __forceinline__ void split2(float x, u16& hi, u16& lo) {
  hi = bf16_rn(x);
  lo = bf16_rn(x - bf16f(hi));
}

// ---- global_load_lds (width 16) --------------------------------------------
// NOTE: proper addrspacecast (generic->AS1 / generic->AS3) via C-style casts.
// (Round-1 version truncated the flat pointer to 32 bits — relies on an
//  undocumented aperture layout; this form is the canonical one.)
__device__ __forceinline__ void gld_lds16(const void* g, void* l) {
  __builtin_amdgcn_global_load_lds(
      (const __attribute__((address_space(1))) uint32_t*)g,
      (__attribute__((address_space(3))) uint32_t*)l,
      16, 0, 0);
}

// LDS tile layout: [128 rows][32 bf16] = 64B/row, 4x 16B slots/row.
// Swizzle (involution): LDS[r][s] holds global slot s ^ ((r>>1)&3).
// global_load_lds dest stays linear (wave-uniform base + lane*16); the
// permutation is applied on the per-lane GLOBAL source address and again on
// the ds_read side (rule #21: both-sides-or-neither).
__device__ __forceinline__ short8 frag_ld(const void* base, int r, int slot) {
  const char* p = (const char*)base + r * 64 + (((slot ^ ((r >> 1) & 3)) & 3) << 4);
  return *(const short8*)p;
}
__device__ __forceinline__ f32x4 mfma16(short8 a, short8 b, f32x4 c) {
  return __builtin_amdgcn_mfma_f32_16x16x32_bf16(
      __builtin_bit_cast(bf16x8, a), __builtin_bit_cast(bf16x8, b), c, 0, 0, 0);
}

// ---------------------------------------------------------------------------
// bf16x3 GEMM, 128x128 tile, BK=32, 256 threads (4 waves, each 64x64).
// C = A*B^T in fp32 via 3 bf16 MFMAs (ah*bh + ah*bl + al*bh), err ~2^-18.
// A: [M][lda] hi/lo bf16 row-major.  B: pre-transposed [N][ldb] hi/lo bf16.
// MODE 0: gates (grid.z = gate; K-extension with h_blk @ R^T[blk]; +bias)
// MODE 1: mlp   (grid.z selects gate_k/up_k via zstB; out P1 / P2)
// MODE 2: down  (+seq residual)
// ---------------------------------------------------------------------------
template<int MODE>
__global__ __launch_bounds__(256, 2) void gemm3(
    const u16* __restrict__ Ah, const u16* __restrict__ Al, int lda,
    const u16* __restrict__ Bh, const u16* __restrict__ Bl, int ldb,
    size_t zstB, int kt1, int kt2,
    const u16* __restrict__ A2h, const u16* __restrict__ A2l,
    const u16* __restrict__ R2h, const u16* __restrict__ R2l,
    const float* __restrict__ b0, const float* __restrict__ b1,
    const float* __restrict__ b2, const float* __restrict__ b3,
    const float* __restrict__ seqres,
    float* __restrict__ out0, float* __restrict__ out1, int ldo) {
  __shared__ u16 AsH[128 * 32], AsL[128 * 32], BsH[128 * 32], BsL[128 * 32];
  const int tid  = threadIdx.x;
  const int lane = tid & 63, wv = tid >> 6;
  const int wr = wv >> 1, wc = wv & 1;
  const int m0 = blockIdx.x * 128, n0 = blockIdx.y * 128;
  const int z  = blockIdx.z;

  const u16* bh = Bh + (size_t)z * zstB;
  const u16* bl = Bl + (size_t)z * zstB;
  float* outp;
  if (MODE == 0)      outp = out0 + (size_t)z * BC;
  else if (MODE == 1) outp = z ? out1 : out0;
  else                outp = out0;

  f32x4 acc[4][4] = {};
  const int NT = kt1 + kt2;

  for (int kt = 0; kt < NT; ++kt) {
    // ---- stage tile kt into LDS (8 global_load_lds per lane-group) ----
    {
      const u16 *sAh, *sAl, *sBh, *sBl;
      size_t la, lb; int rA0, rB0, k0;
      if (MODE == 0 && kt >= kt1) {          // recurrent phase: h_blk @ R^T
        const int g = n0 >> 9;
        k0  = (kt - kt1) * 32;
        sAh = A2h + g * HD; sAl = A2l + g * HD; la = C_DIM; rA0 = m0;
        sBh = R2h + (size_t)z * 1048576 + (size_t)g * 262144;
        sBl = R2l + (size_t)z * 1048576 + (size_t)g * 262144;
        lb = HD; rB0 = n0 & 511;
      } else {
        k0  = kt * 32;
        sAh = Ah; sAl = Al; la = lda; rA0 = m0;
        sBh = bh; sBl = bl; lb = ldb; rB0 = n0;
      }
#pragma unroll
      for (int j = 0; j < 2; ++j) {
        const int rb = wv * 32 + j * 16;           // wave-uniform LDS row base
        const int r  = rb + (lane >> 2);           // this lane's dest row
        const int sl = (lane & 3) ^ ((r >> 1) & 3);// inverse-swizzled src slot
        const size_t ka = (size_t)(rA0 + r) * la + k0 + sl * 8;
        const size_t kb = (size_t)(rB0 + r) * lb + k0 + sl * 8;
        gld_lds16(sAh + ka, (char*)AsH + rb * 64);
        gld_lds16(sAl + ka, (char*)AsL + rb * 64);
        gld_lds16(sBh + kb, (char*)BsH + rb * 64);
        gld_lds16(sBl + kb, (char*)BsL + rb * 64);
      }
    }
    __syncthreads();   // compiler drains vmcnt(0) before s_barrier -> tile ready

    // ---- fragments + 48 MFMAs ----
    const int slot = lane >> 4;                // which 8-elem K-group
    const int rA = wr * 64 + (lane & 15);
    const int rB = wc * 64 + (lane & 15);
    short8 ahf[4], alf[4], bhf[4], blf[4];
#pragma unroll
    for (int m = 0; m < 4; ++m) {
      ahf[m] = frag_ld(AsH, rA + m * 16, slot);
      alf[m] = frag_ld(AsL, rA + m * 16, slot);
    }
#pragma unroll
    for (int n = 0; n < 4; ++n) {
      bhf[n] = frag_ld(BsH, rB + n * 16, slot);
      blf[n] = frag_ld(BsL, rB + n * 16, slot);
    }
#pragma unroll
    for (int m = 0; m < 4; ++m)
#pragma unroll
      for (int n = 0; n < 4; ++n) {
        acc[m][n] = mfma16(ahf[m], bhf[n], acc[m][n]);
        acc[m][n] = mfma16(ahf[m], blf[n], acc[m][n]);
        acc[m][n] = mfma16(alf[m], bhf[n], acc[m][n]);
      }
    __syncthreads();   // protect LDS before next stage overwrites
  }

  // ---- epilogue: C/D layout col=lane&15, row=(lane>>4)*4+q (m89/m91) ----
  const float* bias = nullptr;
  if (MODE == 0) bias = (z == 0) ? b0 : (z == 1) ? b1 : (z == 2) ? b2 : b3;
  const int cl   = lane & 15;
  const int rowb = m0 + wr * 64 + (lane >> 4) * 4;
  const int colb = n0 + wc * 64;
#pragma unroll
  for (int n = 0; n < 4; ++n) {
    const int col = colb + n * 16 + cl;
    float bv = (MODE == 0) ? bias[col] : 0.f;
#pragma unroll
    for (int m = 0; m < 4; ++m) {
#pragma unroll
      for (int q = 0; q < 4; ++q) {
        const int row = rowb + m * 16 + q;
        float v = acc[m][n][q] + bv;
        if (MODE == 2) v += seqres[(size_t)row * C_DIM + col];
        outp[(size_t)row * ldo + col] = v;
      }
    }
  }
}

// ---------------------------------------------------------------------------
// Transpose + hi/lo split: in (K x N) fp32 -> out (N x K) bf16 hi & lo.
// ---------------------------------------------------------------------------
__global__ __launch_bounds__(256) void convert_T(
    const float* __restrict__ in, size_t inZ, int K, int N,
    u16* __restrict__ outH, u16* __restrict__ outL, size_t outZ) {
  __shared__ float t[32][33];
  const float* ip = in + (size_t)blockIdx.z * inZ;
  u16* oh = outH + (size_t)blockIdx.z * outZ;
  u16* ol = outL + (size_t)blockIdx.z * outZ;
  const int k0 = blockIdx.x * 32, n0 = blockIdx.y * 32;
  {
    const int r = threadIdx.x >> 3, c = (threadIdx.x & 7) * 4;
    F4 v; v.v = *(const float4*)(ip + (size_t)(k0 + r) * N + n0 + c);
    t[r][c] = v.f[0]; t[r][c + 1] = v.f[1]; t[r][c + 2] = v.f[2]; t[r][c + 3] = v.f[3];
  }
  __syncthreads();
  const int n = threadIdx.x >> 3, kq = (threadIdx.x & 7) * 4;
  us4 hv, lv;
#pragma unroll
  for (int i = 0; i < 4; ++i) {
    u16 h, l; split2(t[kq + i][n], h, l);
    hv[i] = h; lv[i] = l;
  }
  const size_t o = (size_t)(n0 + n) * K + k0 + kq;
  *(us4*)(oh + o) = hv;
  *(us4*)(ol + o) = lv;
}

// hi/lo split, no transpose (for h_tm1)
__global__ __launch_bounds__(256) void convert_hilo(
    const float* __restrict__ in, u16* __restrict__ oh, u16* __restrict__ ol,
    size_t n4) {
  for (size_t i = (size_t)blockIdx.x * 256 + threadIdx.x; i < n4;
       i += (size_t)gridDim.x * 256) {
    F4 v; v.v = ((const float4*)in)[i];
    us4 hv, lv;
#pragma unroll
    for (int j = 0; j < 4; ++j) { u16 h, l; split2(v.f[j], h, l); hv[j] = h; lv[j] = l; }
    ((us4*)oh)[i] = hv;
    ((us4*)ol)[i] = lv;
  }
}

// ---------------------------------------------------------------------------
// Row LayerNorm -> bf16 hi/lo split output. One block (256 thr) per row.
// ---------------------------------------------------------------------------
template<int W>
__global__ __launch_bounds__(256) void ln_split(
    const float* __restrict__ in, const float* __restrict__ scale,
    u16* __restrict__ oh, u16* __restrict__ ol) {
  constexpr int NV = W / 256 / 4;
  const size_t row = blockIdx.x;
  const float* rp = in + row * (size_t)W;
  F4 v[NV];
  float s = 0.f, q = 0.f;
#pragma unroll
  for (int i = 0; i < NV; ++i) {
    v[i].v = *(const float4*)(rp + (size_t)(i * 256 + threadIdx.x) * 4);
#pragma unroll
    for (int j = 0; j < 4; ++j) { s += v[i].f[j]; q += v[i].f[j] * v[i].f[j]; }
  }
#pragma unroll
  for (int off = 32; off > 0; off >>= 1) { s += __shfl_down(s, off); q += __shfl_down(q, off); }
  __shared__ float red[8];
  if ((threadIdx.x & 63) == 0) { red[(threadIdx.x >> 6) * 2] = s; red[(threadIdx.x >> 6) * 2 + 1] = q; }
  __syncthreads();
  s = red[0] + red[2] + red[4] + red[6];
  q = red[1] + red[3] + red[5] + red[7];
  const float mu  = s * (1.f / W);
  const float var = q * (1.f / W) - mu * mu;
  const float rs  = rsqrtf(var + 1e-6f);
#pragma unroll
  for (int i = 0; i < NV; ++i) {
    const int col = (i * 256 + threadIdx.x) * 4;
    F4 sc; sc.v = *(const float4*)(scale + col);
    us4 hv, lv;
#pragma unroll
    for (int j = 0; j < 4; ++j) {
      u16 h, l; split2((v[i].f[j] - mu) * rs * sc.f[j], h, l);
      hv[j] = h; lv[j] = l;
    }
    *(us4*)(oh + row * (size_t)W + col) = hv;
    *(us4*)(ol + row * (size_t)W + col) = lv;
  }
}

// ---------------------------------------------------------------------------
// GroupNorm(4) + residual: out1 = GN(h)*gn_s + seq (fp32)
// ---------------------------------------------------------------------------
__global__ __launch_bounds__(128) void gn_kernel(
    const float* __restrict__ h, const float* __restrict__ seq,
    const float* __restrict__ gn_s, float* __restrict__ out1) {
  const int b = blockIdx.x >> 2;
  const int g = blockIdx.x & 3;
  const size_t base = (size_t)b * C_DIM + g * HD;
  F4 v; v.v = *(const float4*)(h + base + threadIdx.x * 4);
  float s = v.f[0] + v.f[1] + v.f[2] + v.f[3];
  float q = v.f[0]*v.f[0] + v.f[1]*v.f[1] + v.f[2]*v.f[2] + v.f[3]*v.f[3];
#pragma unroll
  for (int off = 32; off > 0; off >>= 1) { s += __shfl_down(s, off); q += __shfl_down(q, off); }
  __shared__ float red[4];
  if ((threadIdx.x & 63) == 0) {
    red[(threadIdx.x >> 6) * 2] = s; red[(threadIdx.x >> 6) * 2 + 1] = q;
  }
  __syncthreads();
  s = red[0] + red[2]; q = red[1] + red[3];
  const float mu  = s * (1.f / HD);
  const float var = q * (1.f / HD) - mu * mu;
  const float rs  = rsqrtf(var + 1e-6f);
  const int col = g * HD + threadIdx.x * 4;
  F4 sc; sc.v = *(const float4*)(gn_s + col);
  F4 sq; sq.v = *(const float4*)(seq + base + threadIdx.x * 4);
  F4 o;
#pragma unroll
  for (int j = 0; j < 4; ++j) o.f[j] = (v.f[j] - mu) * rs * sc.f[j] + sq.f[j];
  *(float4*)(out1 + base + threadIdx.x * 4) = o.v;
}

// ---------------------------------------------------------------------------
// sLSTM pointwise cell: preacts (z,i,f,o incl. bias) -> c,n,h,m into d_out
// ---------------------------------------------------------------------------
__global__ __launch_bounds__(256) void cell_kernel(
    const float* __restrict__ pre, const float* __restrict__ c1,
    const float* __restrict__ n1, const float* __restrict__ m1,
    float* __restrict__ dout) {
  const size_t n4 = BC / 4;
  for (size_t i = (size_t)blockIdx.x * 256 + threadIdx.x; i < n4;
       i += (size_t)gridDim.x * 256) {
    F4 pz, pi, pf, po, cp, np, mp;
    pz.v = ((const float4*)pre)[i];
    pi.v = ((const float4*)pre)[i + n4];
    pf.v = ((const float4*)pre)[i + 2 * n4];
    po.v = ((const float4*)pre)[i + 3 * n4];
    cp.v = ((const float4*)c1)[i];
    np.v = ((const float4*)n1)[i];
    mp.v = ((const float4*)m1)[i];
    F4 oc, on, oh, om;
#pragma unroll
    for (int j = 0; j < 4; ++j) {
      const float zt = tanhf(pz.f[j]);
      const float mt = fmaxf(pf.f[j] + mp.f[j], pi.f[j]);
      const float ig = expf(pi.f[j] - mt);
      const float fg = expf(pf.f[j] - mt + mp.f[j]);
      const float og = 1.f / (1.f + expf(-po.f[j]));
      const float ct = fg * cp.f[j] + ig * zt;
      const float nt = fg * np.f[j] + ig;
      oc.f[j] = ct; on.f[j] = nt; oh.f[j] = og * (ct / nt); om.f[j] = mt;
    }
    ((float4*)(dout + BC))[i]     = oc.v;
    ((float4*)(dout + 2 * BC))[i] = on.v;
    ((float4*)(dout + 3 * BC))[i] = oh.v;
    ((float4*)(dout + 4 * BC))[i] = om.v;
  }
}

// prod = silu(P1) * P2, in place over P1
__global__ __launch_bounds__(256) void silu_prod(
    float* __restrict__ p1, const float* __restrict__ p2, size_t n4) {
  for (size_t i = (size_t)blockIdx.x * 256 + threadIdx.x; i < n4;
       i += (size_t)gridDim.x * 256) {
    F4 a, b; a.v = ((const float4*)p1)[i]; b.v = ((const float4*)p2)[i];
    F4 o;
#pragma unroll
    for (int j = 0; j < 4; ++j)
      o.f[j] = (a.f[j] / (1.f + expf(-a.f[j]))) * b.f[j];
    ((float4*)p1)[i] = o.v;
  }
}

// ---------------------------------------------------------------------------
extern "C" void kernel_launch(void* const* d_in, const int* in_sizes, int n_in,
                              void* d_out, int out_size, void* d_ws, size_t ws_size,
                              hipStream_t stream) {
  const float* seq   = (const float*)d_in[0];
  const float* c_tm1 = (const float*)d_in[1];
  const float* n_tm1 = (const float*)d_in[2];
  const float* h_tm1 = (const float*)d_in[3];
  const float* m_tm1 = (const float*)d_in[4];
  const float* ln1_s = (const float*)d_in[5];
  const float* Wg[4] = {(const float*)d_in[6], (const float*)d_in[8],
                        (const float*)d_in[10], (const float*)d_in[12]};
  const float* bg[4] = {(const float*)d_in[7], (const float*)d_in[9],
                        (const float*)d_in[11], (const float*)d_in[13]};
  const float* Rg[4] = {(const float*)d_in[14], (const float*)d_in[15],
                        (const float*)d_in[16], (const float*)d_in[17]};
  const float* gn_s     = (const float*)d_in[18];
  const float* ln2_s    = (const float*)d_in[19];
  const float* gate_k   = (const float*)d_in[20];
  const float* up_k     = (const float*)d_in[21];
  const float* mlp_ln_s = (const float*)d_in[22];
  const float* down_k   = (const float*)d_in[23];
  float* out = (float*)d_out;   // [out | c | n | h | m]

  // ---- workspace layout ----------------------------------------------------
  // W1  128 MiB : gate W^T hi/lo (64) + R^T hi/lo (16)  -> MLP gate/up hi/lo
  // W2   64 MiB : down^T hi/lo
  // A1   32 MiB : x hi/lo -> o1 fp32
  // A2   32 MiB : h hi/lo -> y hi/lo
  // BIG 2*half  : preact (128) -> per-chunk [P1 | P2->mid]
  // floor: 384 MiB at NC=2, 512 MiB at NC=1.
  const size_t MiB = 1ull << 20;
  const int NC = (ws_size >= 512 * MiB) ? 1 : 2;
  const size_t halfB = (NC == 1) ? 128 * MiB : 64 * MiB;
  char* W1  = (char*)d_ws;
  char* W2  = W1 + 128 * MiB;
  char* A1  = W2 + 64 * MiB;
  char* A2  = A1 + 32 * MiB;
  char* BIG = A2 + 32 * MiB;

  u16* wtH = (u16*)W1;       u16* wtL = wtH + 16777216;   // 4x 2048x2048
  u16* rtH = wtH + 33554432; u16* rtL = rtH + 4194304;    // 4x 4x 512x512
  u16* gkH = (u16*)W1;       u16* gkL = gkH + 33554432;   // [gate|up]^T hi/lo
  u16* dkH = (u16*)W2;       u16* dkL = dkH + 16777216;   // down^T hi/lo
  u16* xh = (u16*)A1;        u16* xl = xh + BC;
  float* o1 = (float*)A1;
  u16* hh = (u16*)A2;        u16* hl = hh + BC;
  u16* yh = hh;              u16* yl = hl;
  float* preact = (float*)BIG;              // 4*BC fp32 = 128 MiB

  // 1) convert gate weights: W^T hi/lo and R^T hi/lo
  for (int g = 0; g < 4; ++g) {
    convert_T<<<dim3(64, 64, 1), 256, 0, stream>>>(
        Wg[g], 0, C_DIM, C_DIM, wtH + (size_t)g * 4194304, wtL + (size_t)g * 4194304, 0);
    convert_T<<<dim3(16, 16, 4), 256, 0, stream>>>(
        Rg[g], 262144, HD, HD, rtH + (size_t)g * 1048576, rtL + (size_t)g * 1048576, 262144);
  }
  // 2) x = LN(seq) -> hi/lo ; h_tm1 -> hi/lo
  ln_split<C_DIM><<<B_ROWS, 256, 0, stream>>>(seq, ln1_s, xh, xl);
  convert_hilo<<<2048, 256, 0, stream>>>(h_tm1, hh, hl, BC / 4);
  // 3) gates GEMM (x@W^T + h_blk@R^T + bias) -> preacts
  gemm3<0><<<dim3(32, 16, 4), 256, 0, stream>>>(
      xh, xl, C_DIM, wtH, wtL, C_DIM, 4194304ull, 64, 16,
      hh, hl, rtH, rtL, bg[0], bg[1], bg[2], bg[3], nullptr,
      preact, nullptr, C_DIM);
  // 4) cell -> c,n,h,m into d_out
  cell_kernel<<<2048, 256, 0, stream>>>(preact, c_tm1, n_tm1, m_tm1, out);
  // 5) o1 = GN(h_t)*gn_s + seq   (A1; x is dead)
  gn_kernel<<<B_ROWS * 4, 128, 0, stream>>>(out + 3 * BC, seq, gn_s, o1);
  // 6) y = LN(o1) -> hi/lo (A2; h is dead)
  ln_split<C_DIM><<<B_ROWS, 256, 0, stream>>>(o1, ln2_s, yh, yl);
  // 7) convert MLP weights (W1 reused; gate weights dead) + down weights
  convert_T<<<dim3(64, 256, 1), 256, 0, stream>>>(gate_k, 0, C_DIM, F_DIM, gkH, gkL, 0);
  convert_T<<<dim3(64, 256, 1), 256, 0, stream>>>(up_k,   0, C_DIM, F_DIM,
                                                  gkH + 16777216, gkL + 16777216, 0);
  convert_T<<<dim3(256, 64, 1), 256, 0, stream>>>(down_k, 0, F_DIM, C_DIM, dkH, dkL, 0);

  // 8) MLP, chunked over rows (preact dead; BIG holds per-chunk P1 | P2/mid)
  const int Mc = B_ROWS / NC;
  float* P1 = (float*)BIG;                       // Mc*F fp32 = halfB
  float* P2 = (float*)(BIG + halfB);             // Mc*F fp32 = halfB
  u16* midH = (u16*)P2;                          // mid hi/lo overwrites P2
  u16* midL = midH + (size_t)Mc * F_DIM;         // (dead after silu_prod)
  for (int ci = 0; ci < NC; ++ci) {
    const size_t ro = (size_t)ci * Mc;
    gemm3<1><<<dim3(Mc / 128, 64, 2), 256, 0, stream>>>(
        yh + ro * C_DIM, yl + ro * C_DIM, C_DIM,
        gkH, gkL, C_DIM, 16777216ull, 64, 0,
        nullptr, nullptr, nullptr, nullptr,
        nullptr, nullptr, nullptr, nullptr, nullptr,
        P1, P2, F_DIM);
    silu_prod<<<4096, 256, 0, stream>>>(P1, P2, (size_t)Mc * F_DIM / 4);
    ln_split<F_DIM><<<Mc, 256, 0, stream>>>(P1, mlp_ln_s, midH, midL);
    gemm3<2><<<dim3(Mc / 128, 16, 1), 256, 0, stream>>>(
        midH, midL, F_DIM, dkH, dkL, F_DIM, 0ull, 256, 0,
        nullptr, nullptr, nullptr, nullptr,
        nullptr, nullptr, nullptr, nullptr,
        seq + ro * C_DIM,
        out + ro * C_DIM, nullptr, C_DIM);
  }
}